// Round 1
// baseline (1572.211 us; speedup 1.0000x reference)
//
#include <hip/hip_runtime.h>
#include <stdint.h>
#include <stddef.h>

// Problem dims (fixed by reference setup_inputs)
#define M_TOK 8192
#define K_IN  4096
#define N_OUT 11008
// ALPHA/R = 32/16 = 2.0

typedef __attribute__((ext_vector_type(8))) short   short8;   // 8 bf16 (4 VGPRs) — MFMA A/B frag
typedef __attribute__((ext_vector_type(4))) float   floatx4;  // MFMA C/D frag

#define AS1(p) ((const __attribute__((address_space(1))) void*)(p))
#define AS3(p) ((__attribute__((address_space(3))) void*)(p))

__device__ __forceinline__ unsigned short f2bf_rne(float f) {
  union { float f; unsigned u; } v; v.f = f;
  unsigned r = v.u + 0x7FFFu + ((v.u >> 16) & 1u);  // round-to-nearest-even
  return (unsigned short)(r >> 16);
}

__device__ __forceinline__ unsigned long long pack4(float a, float b, float c, float d) {
  return (unsigned long long)f2bf_rne(a)
       | ((unsigned long long)f2bf_rne(b) << 16)
       | ((unsigned long long)f2bf_rne(c) << 32)
       | ((unsigned long long)f2bf_rne(d) << 48);
}

// ---- Kernel 1: cast x (fp32) -> bf16 scratch. float4 in, 8B out per thread.
__global__ void cast_x_kernel(const float* __restrict__ x,
                              unsigned long long* __restrict__ xb) {
  size_t idx = (size_t)blockIdx.x * blockDim.x + threadIdx.x;
  const float4 v = ((const float4*)x)[idx];
  xb[idx] = pack4(v.x, v.y, v.z, v.w);
}

// ---- Kernel 2: W' = bf16(W + 2 * B @ A).  One block = (row o, 1024-col chunk).
__global__ void wprime_kernel(const float* __restrict__ W,
                              const float* __restrict__ B,
                              const float* __restrict__ A,
                              unsigned long long* __restrict__ wp) {
  const int o   = blockIdx.x;
  const int col = blockIdx.y * 1024 + threadIdx.x * 4;
  float4 acc = *(const float4*)(W + (size_t)o * K_IN + col);
#pragma unroll
  for (int r = 0; r < 16; ++r) {
    const float b2 = 2.0f * B[o * 16 + r];   // block-uniform -> scalar load
    const float4 a4 = *(const float4*)(A + (size_t)r * K_IN + col);
    acc.x += b2 * a4.x; acc.y += b2 * a4.y;
    acc.z += b2 * a4.z; acc.w += b2 * a4.w;
  }
  wp[((size_t)o * K_IN + col) >> 2] = pack4(acc.x, acc.y, acc.z, acc.w);
}

// ---- Kernel 3: out[M,N] = Xb[M,K] @ Wp[N,K]^T + bias   (m97 structure)
// 128x128 block tile, BK=32, 4 waves each 64x64 (4x4 of 16x16x32 MFMA).
__global__ __launch_bounds__(256) void lora_gemm(
    const unsigned short* __restrict__ Xb,
    const unsigned short* __restrict__ Wp,
    const float* __restrict__ bias,
    float* __restrict__ out) {
  // Unpadded [128][32]: global_load_lds needs LDS contiguous in lane order.
  __shared__ __align__(16) unsigned short As[128 * 32];
  __shared__ __align__(16) unsigned short Bs[128 * 32];

  const int tid  = threadIdx.x;
  const int m0   = blockIdx.y * 128;
  const int n0   = blockIdx.x * 128;
  const int wid  = tid >> 6;
  const int lane = tid & 63;
  const int wm   = (wid >> 1) * 64;   // wave's m offset in tile
  const int wn   = (wid & 1) * 64;    // wave's n offset in tile
  const int lrow = lane & 15;         // A: m / B: n within 16-tile
  const int quad = lane >> 4;         // k-offset = quad*8

  floatx4 acc[4][4];
#pragma unroll
  for (int i = 0; i < 4; ++i)
#pragma unroll
    for (int j = 0; j < 4; ++j)
      acc[i][j] = (floatx4){0.f, 0.f, 0.f, 0.f};

  // Staging: 512 16B chunks per tile; thread t does chunks t and t+256.
  // chunk ci -> row ci>>2, seg (ci&3)*8 elems. LDS offset = ci*8 elems
  // = wave-uniform + lane*16B (ci is tid-contiguous within a wave).
  const int r0 = tid >> 2;
  const int s0 = (tid & 3) * 8;
  const unsigned short* pa = Xb + (size_t)(m0 + r0) * K_IN + s0;
  const unsigned short* pb = Wp + (size_t)(n0 + r0) * K_IN + s0;

  const unsigned short* pAf = As + (wm + lrow) * 32 + quad * 8;
  const unsigned short* pBf = Bs + (wn + lrow) * 32 + quad * 8;

  for (int kt = 0; kt < K_IN / 32; ++kt) {
    __builtin_amdgcn_global_load_lds(AS1(pa),                    AS3(As + tid * 8),        16, 0, 0);
    __builtin_amdgcn_global_load_lds(AS1(pa + (size_t)64 * K_IN), AS3(As + tid * 8 + 2048), 16, 0, 0);
    __builtin_amdgcn_global_load_lds(AS1(pb),                    AS3(Bs + tid * 8),        16, 0, 0);
    __builtin_amdgcn_global_load_lds(AS1(pb + (size_t)64 * K_IN), AS3(Bs + tid * 8 + 2048), 16, 0, 0);
    pa += 32; pb += 32;
    __syncthreads();

    short8 a[4], b[4];
#pragma unroll
    for (int mi = 0; mi < 4; ++mi)
      a[mi] = *(const short8*)(pAf + mi * 16 * 32);
#pragma unroll
    for (int ni = 0; ni < 4; ++ni)
      b[ni] = *(const short8*)(pBf + ni * 16 * 32);

#pragma unroll
    for (int mi = 0; mi < 4; ++mi)
#pragma unroll
      for (int ni = 0; ni < 4; ++ni)
        acc[mi][ni] = __builtin_amdgcn_mfma_f32_16x16x32_bf16(a[mi], b[ni], acc[mi][ni], 0, 0, 0);

    __syncthreads();
  }

  // Epilogue: C/D layout col = lane&15 (n), row = quad*4 + reg (m). Fuse bias.
  float bv[4];
#pragma unroll
  for (int ni = 0; ni < 4; ++ni)
    bv[ni] = bias[n0 + wn + ni * 16 + lrow];

#pragma unroll
  for (int mi = 0; mi < 4; ++mi) {
    const int rbase = m0 + wm + mi * 16 + quad * 4;
#pragma unroll
    for (int ni = 0; ni < 4; ++ni) {
      const int col = n0 + wn + ni * 16 + lrow;
#pragma unroll
      for (int r = 0; r < 4; ++r)
        out[(size_t)(rbase + r) * N_OUT + col] = acc[mi][ni][r] + bv[ni];
    }
  }
}

extern "C" void kernel_launch(void* const* d_in, const int* in_sizes, int n_in,
                              void* d_out, int out_size, void* d_ws, size_t ws_size,
                              hipStream_t stream) {
  const float* x    = (const float*)d_in[0];
  const float* W    = (const float*)d_in[1];
  const float* bias = (const float*)d_in[2];
  const float* B    = (const float*)d_in[3];
  const float* A    = (const float*)d_in[4];
  float* out = (float*)d_out;

  // Workspace layout: [ x_bf16 : 8192*4096*2 = 64 MiB ][ W'_bf16 : 11008*4096*2 ≈ 86 MiB ]
  unsigned short* xb = (unsigned short*)d_ws;
  unsigned short* wp = (unsigned short*)((char*)d_ws + (size_t)M_TOK * K_IN * 2);

  cast_x_kernel<<<(M_TOK * K_IN / 4) / 256, 256, 0, stream>>>(
      x, (unsigned long long*)xb);
  wprime_kernel<<<dim3(N_OUT, K_IN / 1024), 256, 0, stream>>>(
      W, B, A, (unsigned long long*)wp);
  lora_gemm<<<dim3(N_OUT / 128, M_TOK / 128), 256, 0, stream>>>(
      xb, wp, bias, out);
}